// Round 1
// baseline (328.249 us; speedup 1.0000x reference)
//
#include <hip/hip_runtime.h>

// out[b,i,n] = sum_j w[i,j] * x[b,j,n]
// x: [B=256, 3, N=65536] fp32, w: [3,3] fp32, out: [B, 3, N] fp32.
// Pure streaming map: 402 MB HBM traffic, FLOPs negligible -> HBM-bound.
// Each thread handles one float4 group of n for one batch b:
//   3x float4 loads (rows j=0..2), 9 FMA per component, 3x float4 stores.

#define B_DIM 256
#define N_DIM 65536
#define GPB   (N_DIM / 4)          // float4 groups per (b, j) row = 16384

__global__ __launch_bounds__(256) void rot_kernel(
    const float4* __restrict__ x,
    const float*  __restrict__ w,
    float4*       __restrict__ out)
{
    const long idx = (long)blockIdx.x * blockDim.x + threadIdx.x;
    // idx in [0, B*GPB); GPB is a power of two -> shifts, not divides
    const long b = idx >> 14;           // idx / GPB
    const long g = idx & (GPB - 1);     // idx % GPB

    // 3x3 weight: wave-uniform addresses -> scalar loads, fully cached
    const float w00 = w[0], w01 = w[1], w02 = w[2];
    const float w10 = w[3], w11 = w[4], w12 = w[5];
    const float w20 = w[6], w21 = w[7], w22 = w[8];

    const long base = b * (3 * (long)GPB) + g;
    const float4 x0 = x[base];
    const float4 x1 = x[base + GPB];
    const float4 x2 = x[base + 2 * GPB];

    float4 o0, o1, o2;
    o0.x = fmaf(w00, x0.x, fmaf(w01, x1.x, w02 * x2.x));
    o0.y = fmaf(w00, x0.y, fmaf(w01, x1.y, w02 * x2.y));
    o0.z = fmaf(w00, x0.z, fmaf(w01, x1.z, w02 * x2.z));
    o0.w = fmaf(w00, x0.w, fmaf(w01, x1.w, w02 * x2.w));

    o1.x = fmaf(w10, x0.x, fmaf(w11, x1.x, w12 * x2.x));
    o1.y = fmaf(w10, x0.y, fmaf(w11, x1.y, w12 * x2.y));
    o1.z = fmaf(w10, x0.z, fmaf(w11, x1.z, w12 * x2.z));
    o1.w = fmaf(w10, x0.w, fmaf(w11, x1.w, w12 * x2.w));

    o2.x = fmaf(w20, x0.x, fmaf(w21, x1.x, w22 * x2.x));
    o2.y = fmaf(w20, x0.y, fmaf(w21, x1.y, w22 * x2.y));
    o2.z = fmaf(w20, x0.z, fmaf(w21, x1.z, w22 * x2.z));
    o2.w = fmaf(w20, x0.w, fmaf(w21, x1.w, w22 * x2.w));

    out[base]           = o0;
    out[base + GPB]     = o1;
    out[base + 2 * GPB] = o2;
}

extern "C" void kernel_launch(void* const* d_in, const int* in_sizes, int n_in,
                              void* d_out, int out_size, void* d_ws, size_t ws_size,
                              hipStream_t stream)
{
    const float4* x = (const float4*)d_in[0];
    const float*  w = (const float*)d_in[1];
    float4*       o = (float4*)d_out;

    const long total_groups = (long)B_DIM * GPB;      // 256 * 16384 = 4,194,304
    const int  block = 256;
    const long grid  = total_groups / block;          // 16384 blocks, exact

    rot_kernel<<<dim3((unsigned)grid), dim3(block), 0, stream>>>(x, w, o);
}